// Round 4
// baseline (2484.173 us; speedup 1.0000x reference)
//
#include <hip/hip_runtime.h>

#define TT 500
typedef __attribute__((ext_vector_type(8))) short short8v;
typedef __attribute__((ext_vector_type(4))) short short4v;
typedef __attribute__((ext_vector_type(4))) float float4v;
typedef unsigned short ushort;

__device__ __forceinline__ ushort f2bf(float f) {
  union { float f; unsigned u; } v; v.f = f;
  unsigned r = v.u + 0x7FFFu + ((v.u >> 16) & 1u);
  return (ushort)(r >> 16);
}
__device__ __forceinline__ ushort f2bfr(float f) {
  union { float f; unsigned u; } v; v.f = f;
  return (ushort)((v.u + 0x8000u) >> 16);
}
__device__ __forceinline__ float bf2f(ushort u) {
  union { unsigned u; float f; } v; v.u = ((unsigned)u) << 16;
  return v.f;
}
__device__ __forceinline__ float sigm(float x) {
  return __builtin_amdgcn_rcpf(1.f + __builtin_amdgcn_exp2f(-1.44269504088896341f * x));
}
__device__ __forceinline__ float tanh_f(float x) {
  return 1.f - 2.f * __builtin_amdgcn_rcpf(1.f + __builtin_amdgcn_exp2f(2.88539008177792682f * x));
}
__device__ __forceinline__ void bar_lds() {
  asm volatile("s_waitcnt lgkmcnt(0)\ns_barrier" ::: "memory");
}
template <int CTRL>
__device__ __forceinline__ float dppadd(float v) {
  int a = __builtin_amdgcn_update_dpp(0, __builtin_bit_cast(int, v), CTRL, 0xF, 0xF, true);
  return v + __builtin_bit_cast(float, a);
}
__device__ __forceinline__ float rsum16(float v) {
  v = dppadd<0xB1>(v);
  v = dppadd<0x4E>(v);
  v = dppadd<0x141>(v);
  v = dppadd<0x140>(v);
  return v;
}
__device__ __forceinline__ void wait_flag(int* f) {
  while (__hip_atomic_load(f, __ATOMIC_RELAXED, __HIP_MEMORY_SCOPE_AGENT) == 0)
    __builtin_amdgcn_s_sleep(8);
  __builtin_amdgcn_fence(__ATOMIC_ACQUIRE, "agent");
}
#define MFMA __builtin_amdgcn_mfma_f32_16x16x32_bf16

// ---------------------------------------------------------------------------
__global__ __launch_bounds__(256) void conv_k(
    const float* __restrict__ W1, const float* __restrict__ W2,
    const float* __restrict__ W3, const float* __restrict__ Wih,
    const float* __restrict__ key, const float* __restrict__ Wg,
    const float* __restrict__ Wgg, ushort* __restrict__ wts)
{
  int idx = blockIdx.x * 256 + threadIdx.x;
  if (idx >= 200704) return;
  float v;
  if (idx < 32768)       v = W1[idx];
  else if (idx < 81920)  v = W2[idx - 32768];
  else if (idx < 114688) v = W3[idx - 81920];
  else if (idx < 163840) v = Wih[idx - 114688];
  else if (idx < 167936) v = key[idx - 163840];
  else {
    int j = idx - 167936, o = j >> 7, k = j & 127;
    v = (o < 128) ? Wg[o * 256 + 128 + k] : Wgg[(o - 128) * 256 + 128 + k];
  }
  wts[idx] = f2bf(v);
}

// ---------------------------------------------------------------------------
// mega v4: identical structure to v3 (1024-thread blocks, two batch-units per
// block), but with amdgpu_waves_per_eu(4,4) to pin the register allocator at
// 4 waves/EU = 128 VGPRs. v3's failure was the allocator targeting 8 waves/EU
// (64 VGPRs) -> producer axA/axB (96 regs) and the scan state spilled to
// scratch: FETCH 75->252MB, WRITE 273->559MB, 3x slowdown. The TLP idea
// (2 independent recurrences -> 4 waves/SIMD hide chain/LDS/trans stalls)
// was never actually tested un-spilled.
// ---------------------------------------------------------------------------
#define XS 424
#define SS 648

__global__ __launch_bounds__(1024)
__attribute__((amdgpu_waves_per_eu(4, 4))) void mega_k(
    const int* __restrict__ a_data, const int* __restrict__ e_data,
    const float* __restrict__ qm, const float* __restrict__ semb,
    const float* __restrict__ aemb, const float* __restrict__ eemb,
    const float* __restrict__ b1, const float* __restrict__ b2,
    const float* __restrict__ b3, const float* __restrict__ bih,
    const float* __restrict__ bg, const float* __restrict__ bgg,
    const float* __restrict__ Wp, const float* __restrict__ bp,
    const float* __restrict__ Wp1, const float* __restrict__ bp1,
    const ushort* __restrict__ wts,
    const float* __restrict__ Wf, const float* __restrict__ bf_,
    const float* __restrict__ Wg, const float* __restrict__ Wgg,
    const float* __restrict__ Whh, const float* __restrict__ bhh,
    const float* __restrict__ h0v, const float* __restrict__ m0,
    ushort* __restrict__ gxb, ushort* __restrict__ xgx,
    float* __restrict__ wallb, float* __restrict__ c1b, float* __restrict__ c2b,
    ushort* __restrict__ htsm, ushort* __restrict__ htsg,
    int* __restrict__ flags)
{
  __shared__ __align__(16) ushort pool[27136];
  const int tid = threadIdx.x;
  const int w = tid >> 6, l = tid & 63, jj = l & 15, seg = l >> 4;
  const int u8 = w & 7, unit = w >> 3;
  const int n0 = u8 * 16 + seg * 4;

  if (blockIdx.x < 32) {
    // ================= memory scan (2 batches / block) =================
    __builtin_amdgcn_s_setprio(3);
    const int b = blockIdx.x + unit * 32;
    ushort* h_bf = pool + unit * 4352;
    ushort* htb  = h_bf + 4096;
    ushort* LGb  = h_bf + 4224;

    short8v afrA[4], aggA[4], aggB[4], alg[4];
#pragma unroll
    for (int ks = 0; ks < 4; ++ks) {
      const float* sA = Wf  + (u8 * 16 + jj) * 256 + ks * 32 + seg * 8;
      const float* sB = Wg  + (u8 * 16 + jj) * 256 + ks * 32 + seg * 8;
      const float* sC = Wgg + (u8 * 16 + jj) * 256 + ks * 32 + seg * 8;
      const float* sD = Wf  + (u8 * 16 + jj) * 256 + 128 + ks * 32 + seg * 8;
      short8v a, bb, c, d;
#pragma unroll
      for (int j = 0; j < 8; ++j) {
        a[j] = (short)f2bf(sA[j]); bb[j] = (short)f2bf(sB[j]);
        c[j] = (short)f2bf(sC[j]); d[j] = (short)f2bf(sD[j]);
      }
      afrA[ks] = a; aggA[ks] = bb; aggB[ks] = c; alg[ks] = d;
    }
    const float4v bf4 = *(const float4v*)(bf_ + n0);

    float hreg[2][4];
#pragma unroll
    for (int nt = 0; nt < 2; ++nt) {
      int k = nt * 16 + jj;
      float4v m = *(const float4v*)(m0 + k * 128 + n0);
#pragma unroll
      for (int r = 0; r < 4; ++r) hreg[nt][r] = m[r];
      int p = ((n0 >> 3) + k) & 15;
      short4v pk;
#pragma unroll
      for (int r = 0; r < 4; ++r) pk[r] = (short)f2bf(hreg[nt][r]);
      *(short4v*)(h_bf + k * 128 + p * 8 + (n0 & 7)) = pk;
    }
    wait_flag(flags + b);
    const float* wl = wallb + (size_t)b * TT * 32;
    const ushort* xgp = xgx + (size_t)b * TT * 256;
    float wv0 = wl[jj], wv1 = wl[16 + jj];
    float wn0 = wl[32 + jj], wn1 = wl[48 + jj];
    short4v xcg  = *(const short4v*)(xgp + n0);
    short4v xcgg = *(const short4v*)(xgp + 128 + n0);
    short4v xng  = *(const short4v*)(xgp + 256 + n0);
    short4v xngg = *(const short4v*)(xgp + 384 + n0);
    {
      float4v htp;
#pragma unroll
      for (int r = 0; r < 4; ++r)
        htp[r] = rsum16(wv0 * hreg[0][r] + wv1 * hreg[1][r]);
      if (jj == 0) {
        short4v hp;
#pragma unroll
        for (int r = 0; r < 4; ++r) hp[r] = (short)f2bf(htp[r]);
        *(short4v*)(htb + n0) = hp;
      }
    }
    __syncthreads();

    for (int t = 0; t < TT - 1; ++t) {
      int tw = (t + 2 <= TT - 1) ? (t + 2) : (TT - 1);
      if ((tw & 31) == 0) wait_flag(flags + (tw >> 5) * 64 + b);
      float wf0 = wl[tw * 32 + jj], wf1 = wl[tw * 32 + 16 + jj];
      short4v xfg  = *(const short4v*)(xgp + (size_t)tw * 256 + n0);
      short4v xfgg = *(const short4v*)(xgp + (size_t)tw * 256 + 128 + n0);

      short8v hb[4];
#pragma unroll
      for (int ks = 0; ks < 4; ++ks)
        hb[ks] = *(short8v*)(htb + ks * 32 + seg * 8);

      float4v xg4, xgg4;
#pragma unroll
      for (int r = 0; r < 4; ++r) { xg4[r] = bf2f((ushort)xcg[r]); xgg4[r] = bf2f((ushort)xcgg[r]); }
      float4v dg0 = xg4, dg1 = {0,0,0,0}, gg0 = xgg4, gg1 = {0,0,0,0};
      dg0 = MFMA(aggA[0], hb[0], dg0, 0, 0, 0);
      dg0 = MFMA(aggA[1], hb[1], dg0, 0, 0, 0);
      dg1 = MFMA(aggA[2], hb[2], dg1, 0, 0, 0);
      dg1 = MFMA(aggA[3], hb[3], dg1, 0, 0, 0);
      gg0 = MFMA(aggB[0], hb[0], gg0, 0, 0, 0);
      gg0 = MFMA(aggB[1], hb[1], gg0, 0, 0, 0);
      gg1 = MFMA(aggB[2], hb[2], gg1, 0, 0, 0);
      gg1 = MFMA(aggB[3], hb[3], gg1, 0, 0, 0);

      float lgv[4];
#pragma unroll
      for (int r = 0; r < 4; ++r)
        lgv[r] = tanh_f(dg0[r] + dg1[r]) * sigm(gg0[r] + gg1[r]);
      if (jj == 0) {
        short4v lp;
#pragma unroll
        for (int r = 0; r < 4; ++r) lp[r] = (short)f2bfr(lgv[r]);
        *(short4v*)(LGb + n0) = lp;
      }

      short8v bv0[4], bv1[4];
#pragma unroll
      for (int ks = 0; ks < 4; ++ks) {
        int g = ks * 4 + seg;
        bv0[ks] = *(short8v*)(h_bf + jj * 128 + ((g + jj) & 15) * 8);
        bv1[ks] = *(short8v*)(h_bf + (16 + jj) * 128 + ((g + 16 + jj) & 15) * 8);
      }
      float4v a0A = {0,0,0,0}, a0B = {0,0,0,0}, a1A = {0,0,0,0}, a1B = {0,0,0,0};
      a0A = MFMA(afrA[0], bv0[0], a0A, 0, 0, 0);
      a0A = MFMA(afrA[1], bv0[1], a0A, 0, 0, 0);
      a0B = MFMA(afrA[2], bv0[2], a0B, 0, 0, 0);
      a0B = MFMA(afrA[3], bv0[3], a0B, 0, 0, 0);
      a1A = MFMA(afrA[0], bv1[0], a1A, 0, 0, 0);
      a1A = MFMA(afrA[1], bv1[1], a1A, 0, 0, 0);
      a1B = MFMA(afrA[2], bv1[2], a1B, 0, 0, 0);
      a1B = MFMA(afrA[3], bv1[3], a1B, 0, 0, 0);
      bar_lds();  // B1

      short8v lb[4];
#pragma unroll
      for (int ks = 0; ks < 4; ++ks)
        lb[ks] = *(short8v*)(LGb + ks * 32 + seg * 8);
      float4v dl0 = bf4, dl1 = {0,0,0,0};
      dl0 = MFMA(alg[0], lb[0], dl0, 0, 0, 0);
      dl0 = MFMA(alg[1], lb[1], dl0, 0, 0, 0);
      dl1 = MFMA(alg[2], lb[2], dl1, 0, 0, 0);
      dl1 = MFMA(alg[3], lb[3], dl1, 0, 0, 0);

      float4v htp = {0,0,0,0};
#pragma unroll
      for (int nt = 0; nt < 2; ++nt) {
        float wvv = nt ? wv1 : wv0;
        float wnn = nt ? wn1 : wn0;
#pragma unroll
        for (int r = 0; r < 4; ++r) {
          float a = nt ? (a1A[r] + a1B[r]) : (a0A[r] + a0B[r]);
          float gam = sigm(a + dl0[r] + dl1[r]);
          float hn = fmaf(gam, hreg[nt][r], wvv * lgv[r]);
          hreg[nt][r] = hn;
          htp[r] = fmaf(wnn, hn, htp[r]);
        }
        int k = nt * 16 + jj;
        int p = ((n0 >> 3) + k) & 15;
        short4v pk;
#pragma unroll
        for (int r = 0; r < 4; ++r) pk[r] = (short)f2bfr(hreg[nt][r]);
        *(short4v*)(h_bf + k * 128 + p * 8 + (n0 & 7)) = pk;
      }
#pragma unroll
      for (int r = 0; r < 4; ++r) htp[r] = rsum16(htp[r]);
      if (jj == 0) {
        short4v hp;
#pragma unroll
        for (int r = 0; r < 4; ++r) hp[r] = (short)f2bfr(htp[r]);
        *(short4v*)(htb + n0) = hp;
        *(short4v*)(htsm + ((size_t)b * TT + t) * 128 + n0) = hp;
      }
      wv0 = wn0; wv1 = wn1; wn0 = wf0; wn1 = wf1;
      xcg = xng; xcgg = xngg; xng = xfg; xngg = xfgg;
      bar_lds();  // B2
    }
  } else if (blockIdx.x < 64) {
    // ================= GRU (2 batches / block) =================
    __builtin_amdgcn_s_setprio(3);
    const int b = (blockIdx.x - 32) + unit * 32;
    ushort* hb2 = pool + unit * 4352;

    short8v wfr[3][4];
    float4v bfr[3];
#pragma unroll
    for (int i = 0; i < 3; ++i) {
      int Mt = u8 + i * 8;
#pragma unroll
      for (int ks = 0; ks < 4; ++ks) {
        const float* src = Whh + (Mt * 16 + jj) * 128 + ks * 32 + seg * 8;
        short8v tv;
#pragma unroll
        for (int j = 0; j < 8; ++j) tv[j] = (short)f2bf(src[j]);
        wfr[i][ks] = tv;
      }
      bfr[i] = *(const float4v*)(bhh + Mt * 16 + seg * 4);
    }
    float4v hj4 = *(const float4v*)(h0v + n0);
    if (jj == 0) {
      short4v hp;
#pragma unroll
      for (int r = 0; r < 4; ++r) hp[r] = (short)f2bf(hj4[r]);
      *(short4v*)(hb2 + n0) = hp;
    }
    wait_flag(flags + b);
    const ushort* gpb = gxb + (size_t)b * TT * 384;
    short4v xr_c = *(const short4v*)(gpb + n0);
    short4v xz_c = *(const short4v*)(gpb + 128 + n0);
    short4v xn_c = *(const short4v*)(gpb + 256 + n0);
    short4v xr_n = *(const short4v*)(gpb + 384 + n0);
    short4v xz_n = *(const short4v*)(gpb + 512 + n0);
    short4v xn_n = *(const short4v*)(gpb + 640 + n0);
    __syncthreads();

    for (int t = 0; t < TT - 1; ++t) {
      int tf = (t + 2 < TT - 1) ? (t + 2) : (TT - 2);
      if ((tf & 31) == 0) wait_flag(flags + (tf >> 5) * 64 + b);
      const ushort* gf = gpb + (size_t)tf * 384;
      short4v xr_f = *(const short4v*)(gf + n0);
      short4v xz_f = *(const short4v*)(gf + 128 + n0);
      short4v xn_f = *(const short4v*)(gf + 256 + n0);

      const ushort* hsrc = hb2 + (t & 1) * 128;
      short8v bfrg[4];
#pragma unroll
      for (int ks = 0; ks < 4; ++ks)
        bfrg[ks] = *(short8v*)(hsrc + ks * 32 + seg * 8);

      float4v a0A = bfr[0], a1A = bfr[1], a2A = bfr[2];
      float4v a0B = {0,0,0,0}, a1B = {0,0,0,0}, a2B = {0,0,0,0};
      a0A = MFMA(wfr[0][0], bfrg[0], a0A, 0, 0, 0);
      a0A = MFMA(wfr[0][1], bfrg[1], a0A, 0, 0, 0);
      a0B = MFMA(wfr[0][2], bfrg[2], a0B, 0, 0, 0);
      a0B = MFMA(wfr[0][3], bfrg[3], a0B, 0, 0, 0);
      a1A = MFMA(wfr[1][0], bfrg[0], a1A, 0, 0, 0);
      a1A = MFMA(wfr[1][1], bfrg[1], a1A, 0, 0, 0);
      a1B = MFMA(wfr[1][2], bfrg[2], a1B, 0, 0, 0);
      a1B = MFMA(wfr[1][3], bfrg[3], a1B, 0, 0, 0);
      a2A = MFMA(wfr[2][0], bfrg[0], a2A, 0, 0, 0);
      a2A = MFMA(wfr[2][1], bfrg[1], a2A, 0, 0, 0);
      a2B = MFMA(wfr[2][2], bfrg[2], a2B, 0, 0, 0);
      a2B = MFMA(wfr[2][3], bfrg[3], a2B, 0, 0, 0);

      ushort* hdst = hb2 + ((t + 1) & 1) * 128;
      short4v hp;
#pragma unroll
      for (int r = 0; r < 4; ++r) {
        float rr = sigm(bf2f((ushort)xr_c[r]) + a0A[r] + a0B[r]);
        float zz = sigm(bf2f((ushort)xz_c[r]) + a1A[r] + a1B[r]);
        float nn = tanh_f(bf2f((ushort)xn_c[r]) + rr * (a2A[r] + a2B[r]));
        hj4[r] = fmaf(1.f - zz, nn, zz * hj4[r]);
        hp[r] = (short)f2bfr(hj4[r]);
      }
      if (jj == 0) {
        *(short4v*)(hdst + n0) = hp;
        *(short4v*)(htsg + ((size_t)b * TT + t) * 128 + n0) = hp;
      }
      xr_c = xr_n; xz_c = xz_n; xn_c = xn_n;
      xr_n = xr_f; xz_n = xz_f; xn_n = xn_f;
      bar_lds();
    }
  } else {
    // ================= phase1 producer (16 waves / unit) =================
    __builtin_amdgcn_s_setprio(0);
    const int gi = blockIdx.x - 64;
    const int chunk = gi >> 6, b = gi & 63;
    const int t0 = chunk * 32;
    const int NT = (TT - t0 < 32) ? (TT - t0) : 32;
    ushort* Xl = pool;
    ushort* Yl = pool + 13568;
    ushort* St = pool;
    const ushort* w1b  = wts;
    const ushort* w2b  = wts + 32768;
    const ushort* w3b  = wts + 81920;
    const ushort* wihb = wts + 114688;
    const ushort* keyb = wts + 163840;
    const ushort* wgb  = wts + 167936;

    {
      // gather: 32 lanes per token, 32 tokens over 1024 threads
      const int tok = tid >> 5, l32 = tid & 31;
      const int tsrc = (tok < NT) ? tok : (NT - 1);
      const int gt = b * TT + t0 + tsrc;
      const int e = e_data[gt], a = a_data[gt];
      const float* qrow = qm + (size_t)e * 101;
      float qv[4];
#pragma unroll
      for (int i = 0; i < 4; ++i) {
        int s = l32 + 32 * i;
        qv[i] = (s < 101) ? qrow[s] : 0.f;
      }
      const float* sbase = semb + l32 * 4;
      float4v acc = {0,0,0,0};
      float cnt = 0.f;
#pragma unroll
      for (int i = 0; i < 4; ++i) {
        unsigned long long bal = __ballot(qv[i] != 0.f);
        unsigned m = (unsigned)(bal >> (tid & 32));
        cnt += (float)__popc(m);
        while (m) {
          int s = 32 * i + __builtin_ctz(m);
          m &= m - 1;
          acc += *(const float4v*)(sbase + s * 128);
        }
      }
      float inv = 1.f / fmaxf(cnt, 1.f);
      ushort* xr = Xl + tok * XS + l32 * 4;
#pragma unroll
      for (int r = 0; r < 4; ++r) xr[r] = f2bf(acc[r] * inv);
      const float* ee = eemb + (size_t)e * 128 + l32 * 4;
      const float* ae = aemb + a * 128 + l32 * 4;
#pragma unroll
      for (int r = 0; r < 4; ++r) { xr[128 + r] = f2bf(ee[r]); xr[256 + r] = f2bf(ae[r]); }
    }
    __syncthreads();

    if (tid < 32) {
      int tau = tid;
      if (tau < NT) {
        const ushort* xr = Xl + tau * XS + 128;
        const float* wv = Wp + 256;
        float a0 = bp[0], a1 = 0.f, a2 = 0.f, a3 = 0.f;
        for (int j = 0; j < 128; j += 4) {
          a0 = fmaf(wv[j],     bf2f(xr[j]),     a0);
          a1 = fmaf(wv[j + 1], bf2f(xr[j + 1]), a1);
          a2 = fmaf(wv[j + 2], bf2f(xr[j + 2]), a2);
          a3 = fmaf(wv[j + 3], bf2f(xr[j + 3]), a3);
        }
        c1b[b * TT + t0 + tau] = (a0 + a1) + (a2 + a3);
      }
    }

    short8v axA[12], axB[12];
#pragma unroll
    for (int i = 0; i < 12; ++i) {
      axA[i] = *(short8v*)(Xl + jj * XS + i * 32 + seg * 8);
      axB[i] = *(short8v*)(Xl + (16 + jj) * XS + i * 32 + seg * 8);
    }

    for (int T = w; T < 24; T += 16) {
      float4v dA = {0,0,0,0}, dB = {0,0,0,0};
      float bv;
      if (T < 8) {
        const ushort* Bp = w1b + (T * 16 + jj) * 256 + seg * 8;
        bv = b1[T * 16 + jj];
#pragma unroll
        for (int k = 0; k < 8; ++k) {
          short8v bw = *(const short8v*)(Bp + k * 32);
          dA = MFMA(axA[k], bw, dA, 0, 0, 0);
          dB = MFMA(axB[k], bw, dB, 0, 0, 0);
        }
      } else if (T < 16) {
        const ushort* Bp = w2b + ((T - 8) * 16 + jj) * 384 + seg * 8;
        bv = b2[(T - 8) * 16 + jj];
#pragma unroll
        for (int k = 0; k < 12; ++k) {
          short8v bw = *(const short8v*)(Bp + k * 32);
          dA = MFMA(axA[k], bw, dA, 0, 0, 0);
          dB = MFMA(axB[k], bw, dB, 0, 0, 0);
        }
      } else {
        const ushort* Bp = w3b + ((T - 16) * 16 + jj) * 256 + seg * 8;
        bv = b3[(T - 16) * 16 + jj];
#pragma unroll
        for (int k = 0; k < 8; ++k) {
          short8v bw = *(const short8v*)(Bp + k * 32);
          dA = MFMA(axA[4 + k], bw, dA, 0, 0, 0);
          dB = MFMA(axB[4 + k], bw, dB, 0, 0, 0);
        }
      }
#pragma unroll
      for (int r = 0; r < 4; ++r) {
        float yA = dA[r] + bv, yB = dB[r] + bv;
        Yl[(seg * 4 + r) * XS + T * 16 + jj]      = f2bf(yA > 0.f ? yA : 0.f);
        Yl[(16 + seg * 4 + r) * XS + T * 16 + jj] = f2bf(yB > 0.f ? yB : 0.f);
      }
    }
    __syncthreads();

    short8v ayA[12], ayB[12];
#pragma unroll
    for (int i = 0; i < 12; ++i) {
      ayA[i] = *(short8v*)(Yl + jj * XS + i * 32 + seg * 8);
      ayB[i] = *(short8v*)(Yl + (16 + jj) * XS + i * 32 + seg * 8);
    }
    if (tid >= 32 && tid < 64) {
      int tau = tid - 32;
      if (tau < NT) {
        const ushort* xr = Yl + tau * XS;
        const float* wv = Wp1 + 256;
        float a0 = bp1[0], a1 = 0.f, a2 = 0.f, a3 = 0.f;
        for (int j = 0; j < 128; j += 4) {
          a0 = fmaf(wv[j],     bf2f(xr[j]),     a0);
          a1 = fmaf(wv[j + 1], bf2f(xr[j + 1]), a1);
          a2 = fmaf(wv[j + 2], bf2f(xr[j + 2]), a2);
          a3 = fmaf(wv[j + 3], bf2f(xr[j + 3]), a3);
        }
        c2b[b * TT + t0 + tau] = (a0 + a1) + (a2 + a3);
      }
    }
    __syncthreads();

    for (int T = w; T < 42; T += 16) {
      const ushort* Bp; int ai;
      if (T < 24)      { Bp = wihb + (T * 16 + jj) * 128 + seg * 8;        ai = 8; }
      else if (T < 40) { Bp = wgb  + ((T - 24) * 16 + jj) * 128 + seg * 8; ai = 4; }
      else             { Bp = keyb + ((T - 40) * 16 + jj) * 128 + seg * 8; ai = 0; }
      float4v dA = {0,0,0,0}, dB = {0,0,0,0};
#pragma unroll
      for (int k = 0; k < 4; ++k) {
        short8v bw = *(const short8v*)(Bp + k * 32);
        dA = MFMA(ayA[ai + k], bw, dA, 0, 0, 0);
        dB = MFMA(ayB[ai + k], bw, dB, 0, 0, 0);
      }
      if (T < 40) {
        float bv = (T < 24) ? bih[T * 16 + jj]
                 : (T < 32) ? bg[(T - 24) * 16 + jj] : bgg[(T - 32) * 16 + jj];
        int col = (T < 24) ? (T * 16 + jj) : (384 + (T - 24) * 16 + jj);
#pragma unroll
        for (int r = 0; r < 4; ++r) {
          St[(seg * 4 + r) * SS + col]      = f2bf(dA[r] + bv);
          St[(16 + seg * 4 + r) * SS + col] = f2bf(dB[r] + bv);
        }
      } else {
#pragma unroll
        for (int r = 0; r < 4; ++r) {
          int tokA = seg * 4 + r, tokB = 16 + seg * 4 + r;
          if (tokA < NT)
            wallb[((size_t)(b * TT + t0 + tokA)) * 32 + (T - 40) * 16 + jj] = dA[r];
          if (tokB < NT)
            wallb[((size_t)(b * TT + t0 + tokB)) * 32 + (T - 40) * 16 + jj] = dB[r];
        }
      }
    }
    __syncthreads();

    {
      const int tok = tid >> 4, sg = tid & 15;
      if (tok < NT) {
        size_t gt = (size_t)b * TT + t0 + tok;
#pragma unroll
        for (int p = 0; p < 3; ++p)
          *(short8v*)(gxb + gt * 384 + sg * 24 + p * 8) = *(short8v*)(St + tok * SS + sg * 24 + p * 8);
#pragma unroll
        for (int p = 0; p < 2; ++p)
          *(short8v*)(xgx + gt * 256 + sg * 16 + p * 8) = *(short8v*)(St + tok * SS + 384 + sg * 16 + p * 8);
      }
    }
    __syncthreads();
    if (tid == 0)
      __hip_atomic_store(flags + chunk * 64 + b, 1, __ATOMIC_RELEASE, __HIP_MEMORY_SCOPE_AGENT);
  }
}

// ---------------------------------------------------------------------------
// combine v2: 256 blocks (4/batch), 16 lanes per tau, vector loads + DPP reduce
// ---------------------------------------------------------------------------
__global__ __launch_bounds__(256) void combine_k(
    const ushort* __restrict__ htsg, const ushort* __restrict__ htsm,
    const float* __restrict__ c1b, const float* __restrict__ c2b,
    const float* __restrict__ Wp, const float* __restrict__ Wp1,
    float* __restrict__ out)
{
  const int b = blockIdx.x >> 2, q = blockIdx.x & 3;
  const int tid = threadIdx.x;
  const int wv = tid >> 6, l = tid & 63, slot = l >> 4, e = l & 15;
  float wpg[8], wpm[8], vpg[8], vpm[8];
#pragma unroll
  for (int r = 0; r < 8; ++r) {
    wpg[r] = Wp[e * 8 + r];  wpm[r] = Wp[128 + e * 8 + r];
    vpg[r] = Wp1[e * 8 + r]; vpm[r] = Wp1[128 + e * 8 + r];
  }
  if (q == 0 && tid == 0) out[(size_t)b * TT] = 0.f;
  const int tbeg = q * 125;
  const int tend = (tbeg + 125 < TT - 1) ? (tbeg + 125) : (TT - 1);
  for (int tau = tbeg + wv * 4 + slot; tau < tend; tau += 16) {
    size_t base = ((size_t)b * TT + tau) * 128;
    short8v hg = *(const short8v*)(htsg + base + e * 8);
    short8v hm = *(const short8v*)(htsm + base + e * 8);
    float qa = 0.f, qb = 0.f;
#pragma unroll
    for (int r = 0; r < 8; ++r) {
      float g = bf2f((ushort)hg[r]), m = bf2f((ushort)hm[r]);
      qa = fmaf(g, wpg[r], fmaf(m, wpm[r], qa));
      qb = fmaf(g, vpg[r], fmaf(m, vpm[r], qb));
    }
    qa = rsum16(qa);
    qb = rsum16(qb);
    if (e == 0) {
      size_t idx = (size_t)b * TT + tau + 1;
      out[idx] = sigm(qa + c1b[idx]) * sigm(qb + c2b[idx]);
    }
  }
}

// ---------------------------------------------------------------------------
extern "C" void kernel_launch(void* const* d_in, const int* in_sizes, int n_in,
                              void* d_out, int out_size, void* d_ws, size_t ws_size,
                              hipStream_t stream) {
  (void)in_sizes; (void)n_in; (void)out_size; (void)ws_size;
  const int* a_data = (const int*)d_in[1];
  const int* e_data = (const int*)d_in[2];
  const float* qm   = (const float*)d_in[4];
  const float* semb = (const float*)d_in[5];
  const float* aemb = (const float*)d_in[6];
  const float* eemb = (const float*)d_in[7];
  const float* W1 = (const float*)d_in[8];   const float* b1 = (const float*)d_in[9];
  const float* W2 = (const float*)d_in[10];  const float* b2 = (const float*)d_in[11];
  const float* W3 = (const float*)d_in[12];  const float* b3 = (const float*)d_in[13];
  const float* key = (const float*)d_in[14];
  const float* Wih = (const float*)d_in[15]; const float* Whh = (const float*)d_in[16];
  const float* bih = (const float*)d_in[17]; const float* bhh = (const float*)d_in[18];
  const float* Wg  = (const float*)d_in[19]; const float* bg  = (const float*)d_in[20];
  const float* Wgg = (const float*)d_in[21]; const float* bgg = (const float*)d_in[22];
  const float* Wf  = (const float*)d_in[23]; const float* bf_ = (const float*)d_in[24];
  const float* Wp  = (const float*)d_in[25]; const float* bp  = (const float*)d_in[26];
  const float* Wp1 = (const float*)d_in[27]; const float* bp1 = (const float*)d_in[28];
  const float* h0v = (const float*)d_in[29]; const float* m0  = (const float*)d_in[30];

  char* ws = (char*)d_ws;
  ushort* gxb  = (ushort*)(ws + 0);
  ushort* xgx  = (ushort*)(ws + 24576000);
  float* wallb = (float*)(ws + 40960000);
  ushort* htsm = (ushort*)(ws + 45056000);
  ushort* htsg = (ushort*)(ws + 53248000);
  float* c1b   = (float*)(ws + 61440000);
  float* c2b   = (float*)(ws + 61568000);
  ushort* wts  = (ushort*)(ws + 61696000);
  int* flags   = (int*)(ws + 62097408);
  float* out = (float*)d_out;

  hipMemsetAsync(flags, 0, 1024 * sizeof(int), stream);
  conv_k<<<dim3(784), dim3(256), 0, stream>>>(W1, W2, W3, Wih, key, Wg, Wgg, wts);
  mega_k<<<dim3(1088), dim3(1024), 0, stream>>>(
      a_data, e_data, qm, semb, aemb, eemb, b1, b2, b3, bih, bg, bgg,
      Wp, bp, Wp1, bp1, wts, Wf, bf_, Wg, Wgg, Whh, bhh, h0v, m0,
      gxb, xgx, wallb, c1b, c2b, htsm, htsg, flags);
  combine_k<<<dim3(256), dim3(256), 0, stream>>>(
      htsg, htsm, c1b, c2b, Wp, Wp1, out);
}

// Round 5
// 1367.909 us; speedup vs baseline: 1.8160x; 1.8160x over previous
//
#include <hip/hip_runtime.h>

#define TT 500
typedef __attribute__((ext_vector_type(8))) short short8v;
typedef __attribute__((ext_vector_type(4))) short short4v;
typedef __attribute__((ext_vector_type(4))) float float4v;
typedef unsigned short ushort;

__device__ __forceinline__ ushort f2bf(float f) {
  union { float f; unsigned u; } v; v.f = f;
  unsigned r = v.u + 0x7FFFu + ((v.u >> 16) & 1u);
  return (ushort)(r >> 16);
}
__device__ __forceinline__ ushort f2bfr(float f) {
  union { float f; unsigned u; } v; v.f = f;
  return (ushort)((v.u + 0x8000u) >> 16);
}
__device__ __forceinline__ float bf2f(ushort u) {
  union { unsigned u; float f; } v; v.u = ((unsigned)u) << 16;
  return v.f;
}
__device__ __forceinline__ float sigm(float x) {
  return __builtin_amdgcn_rcpf(1.f + __builtin_amdgcn_exp2f(-1.44269504088896341f * x));
}
__device__ __forceinline__ float tanh_f(float x) {
  return 1.f - 2.f * __builtin_amdgcn_rcpf(1.f + __builtin_amdgcn_exp2f(2.88539008177792682f * x));
}
__device__ __forceinline__ void bar_lds() {
  asm volatile("s_waitcnt lgkmcnt(0)\ns_barrier" ::: "memory");
}
template <int CTRL>
__device__ __forceinline__ float dppadd(float v) {
  int a = __builtin_amdgcn_update_dpp(0, __builtin_bit_cast(int, v), CTRL, 0xF, 0xF, true);
  return v + __builtin_bit_cast(float, a);
}
__device__ __forceinline__ float rsum16(float v) {
  v = dppadd<0xB1>(v);
  v = dppadd<0x4E>(v);
  v = dppadd<0x141>(v);
  v = dppadd<0x140>(v);
  return v;
}
__device__ __forceinline__ void wait_flag(int* f) {
  while (__hip_atomic_load(f, __ATOMIC_RELAXED, __HIP_MEMORY_SCOPE_AGENT) == 0)
    __builtin_amdgcn_s_sleep(8);
  __builtin_amdgcn_fence(__ATOMIC_ACQUIRE, "agent");
}
#define MFMA __builtin_amdgcn_mfma_f32_16x16x32_bf16

// ---------------------------------------------------------------------------
__global__ __launch_bounds__(256) void conv_k(
    const float* __restrict__ W1, const float* __restrict__ W2,
    const float* __restrict__ W3, const float* __restrict__ Wih,
    const float* __restrict__ key, const float* __restrict__ Wg,
    const float* __restrict__ Wgg, ushort* __restrict__ wts)
{
  int idx = blockIdx.x * 256 + threadIdx.x;
  if (idx >= 200704) return;
  float v;
  if (idx < 32768)       v = W1[idx];
  else if (idx < 81920)  v = W2[idx - 32768];
  else if (idx < 114688) v = W3[idx - 81920];
  else if (idx < 163840) v = Wih[idx - 114688];
  else if (idx < 167936) v = key[idx - 163840];
  else {
    int j = idx - 167936, o = j >> 7, k = j & 127;
    v = (o < 128) ? Wg[o * 256 + 128 + k] : Wgg[(o - 128) * 256 + 128 + k];
  }
  wts[idx] = f2bf(v);
}

// ---------------------------------------------------------------------------
// mega v5: 512-thread blocks (the proven r0 vehicle — allocator behaves at
// this size), but scan/GRU blocks each process TWO batches (b0, b0+32) as
// ILP within the same 8 waves. Weights (64 VGPRs) are batch-shared; only
// small per-batch state doubles. Two independent dependency chains per
// phase fill each other's latency stalls; barriers amortize over 2 steps.
//   blocks 0..31  : mem-scan, batches b0 and b0+32
//   blocks 32..63 : GRU, same pairing
//   blocks 64..1087: phase1 producers (unchanged from r0)
// Per-batch op order is bit-identical to r0 -> absmax unchanged.
// ---------------------------------------------------------------------------
#define XS 424
#define SS 648

__global__ __launch_bounds__(512, 2) void mega_k(
    const int* __restrict__ a_data, const int* __restrict__ e_data,
    const float* __restrict__ qm, const float* __restrict__ semb,
    const float* __restrict__ aemb, const float* __restrict__ eemb,
    const float* __restrict__ b1, const float* __restrict__ b2,
    const float* __restrict__ b3, const float* __restrict__ bih,
    const float* __restrict__ bg, const float* __restrict__ bgg,
    const float* __restrict__ Wp, const float* __restrict__ bp,
    const float* __restrict__ Wp1, const float* __restrict__ bp1,
    const ushort* __restrict__ wts,
    const float* __restrict__ Wf, const float* __restrict__ bf_,
    const float* __restrict__ Wg, const float* __restrict__ Wgg,
    const float* __restrict__ Whh, const float* __restrict__ bhh,
    const float* __restrict__ h0v, const float* __restrict__ m0,
    ushort* __restrict__ gxb, ushort* __restrict__ xgx,
    float* __restrict__ wallb, float* __restrict__ c1b, float* __restrict__ c2b,
    ushort* __restrict__ htsm, ushort* __restrict__ htsg,
    int* __restrict__ flags)
{
  __shared__ __align__(16) ushort pool[27136];
  const int tid = threadIdx.x;
  const int w = tid >> 6, l = tid & 63, jj = l & 15, seg = l >> 4;
  const int n0 = w * 16 + seg * 4;

  if (blockIdx.x < 32) {
    // ================= memory scan (2 batches, ILP) =================
    __builtin_amdgcn_s_setprio(3);
    const int b0 = blockIdx.x;

    short8v afrA[4], aggA[4], aggB[4], alg[4];
#pragma unroll
    for (int ks = 0; ks < 4; ++ks) {
      const float* sA = Wf  + (w * 16 + jj) * 256 + ks * 32 + seg * 8;
      const float* sB = Wg  + (w * 16 + jj) * 256 + ks * 32 + seg * 8;
      const float* sC = Wgg + (w * 16 + jj) * 256 + ks * 32 + seg * 8;
      const float* sD = Wf  + (w * 16 + jj) * 256 + 128 + ks * 32 + seg * 8;
      short8v a, bb, c, d;
#pragma unroll
      for (int j = 0; j < 8; ++j) {
        a[j] = (short)f2bf(sA[j]); bb[j] = (short)f2bf(sB[j]);
        c[j] = (short)f2bf(sC[j]); d[j] = (short)f2bf(sD[j]);
      }
      afrA[ks] = a; aggA[ks] = bb; aggB[ks] = c; alg[ks] = d;
    }
    const float4v bf4 = *(const float4v*)(bf_ + n0);

    float hreg[2][2][4];
#pragma unroll
    for (int q = 0; q < 2; ++q) {
      ushort* h_bf = pool + q * 4352;
#pragma unroll
      for (int nt = 0; nt < 2; ++nt) {
        int k = nt * 16 + jj;
        float4v m = *(const float4v*)(m0 + k * 128 + n0);
#pragma unroll
        for (int r = 0; r < 4; ++r) hreg[q][nt][r] = m[r];
        int p = ((n0 >> 3) + k) & 15;
        short4v pk;
#pragma unroll
        for (int r = 0; r < 4; ++r) pk[r] = (short)f2bf(hreg[q][nt][r]);
        *(short4v*)(h_bf + k * 128 + p * 8 + (n0 & 7)) = pk;
      }
    }

    const float* wl[2];
    const ushort* xgp[2];
    float wv0[2], wv1[2], wn0[2], wn1[2];
    short4v xcg[2], xcgg[2], xng[2], xngg[2];
#pragma unroll
    for (int q = 0; q < 2; ++q) {
      const int b = b0 + q * 32;
      wait_flag(flags + b);
      wl[q]  = wallb + (size_t)b * TT * 32;
      xgp[q] = xgx + (size_t)b * TT * 256;
      wv0[q] = wl[q][jj];      wv1[q] = wl[q][16 + jj];
      wn0[q] = wl[q][32 + jj]; wn1[q] = wl[q][48 + jj];
      xcg[q]  = *(const short4v*)(xgp[q] + n0);
      xcgg[q] = *(const short4v*)(xgp[q] + 128 + n0);
      xng[q]  = *(const short4v*)(xgp[q] + 256 + n0);
      xngg[q] = *(const short4v*)(xgp[q] + 384 + n0);
      float4v htp;
#pragma unroll
      for (int r = 0; r < 4; ++r)
        htp[r] = rsum16(wv0[q] * hreg[q][0][r] + wv1[q] * hreg[q][1][r]);
      if (jj == 0) {
        short4v hp;
#pragma unroll
        for (int r = 0; r < 4; ++r) hp[r] = (short)f2bf(htp[r]);
        *(short4v*)(pool + q * 4352 + 4096 + n0) = hp;
      }
    }
    __syncthreads();

    for (int t = 0; t < TT - 1; ++t) {
      int tw = (t + 2 <= TT - 1) ? (t + 2) : (TT - 1);
      float wf0[2], wf1[2];
      short4v xfg[2], xfgg[2];
      float lgv[2][4];
      float4v a0A[2], a0B[2], a1A[2], a1B[2];

      // ---- phase 1 (both batches): dg/gg MFMAs, lgv, LG publish, gam MFMAs
#pragma unroll
      for (int q = 0; q < 2; ++q) {
        const int b = b0 + q * 32;
        ushort* h_bf = pool + q * 4352;
        ushort* htb  = h_bf + 4096;
        ushort* LGb  = h_bf + 4224;
        if ((tw & 31) == 0) wait_flag(flags + (tw >> 5) * 64 + b);
        wf0[q] = wl[q][tw * 32 + jj]; wf1[q] = wl[q][tw * 32 + 16 + jj];
        xfg[q]  = *(const short4v*)(xgp[q] + (size_t)tw * 256 + n0);
        xfgg[q] = *(const short4v*)(xgp[q] + (size_t)tw * 256 + 128 + n0);

        short8v hb[4];
#pragma unroll
        for (int ks = 0; ks < 4; ++ks)
          hb[ks] = *(short8v*)(htb + ks * 32 + seg * 8);

        float4v xg4, xgg4;
#pragma unroll
        for (int r = 0; r < 4; ++r) {
          xg4[r] = bf2f((ushort)xcg[q][r]);
          xgg4[r] = bf2f((ushort)xcgg[q][r]);
        }
        float4v dg0 = xg4, dg1 = {0,0,0,0}, gg0 = xgg4, gg1 = {0,0,0,0};
        dg0 = MFMA(aggA[0], hb[0], dg0, 0, 0, 0);
        dg0 = MFMA(aggA[1], hb[1], dg0, 0, 0, 0);
        dg1 = MFMA(aggA[2], hb[2], dg1, 0, 0, 0);
        dg1 = MFMA(aggA[3], hb[3], dg1, 0, 0, 0);
        gg0 = MFMA(aggB[0], hb[0], gg0, 0, 0, 0);
        gg0 = MFMA(aggB[1], hb[1], gg0, 0, 0, 0);
        gg1 = MFMA(aggB[2], hb[2], gg1, 0, 0, 0);
        gg1 = MFMA(aggB[3], hb[3], gg1, 0, 0, 0);

#pragma unroll
        for (int r = 0; r < 4; ++r)
          lgv[q][r] = tanh_f(dg0[r] + dg1[r]) * sigm(gg0[r] + gg1[r]);
        if (jj == 0) {
          short4v lp;
#pragma unroll
          for (int r = 0; r < 4; ++r) lp[r] = (short)f2bfr(lgv[q][r]);
          *(short4v*)(LGb + n0) = lp;
        }

        short8v bv0[4], bv1[4];
#pragma unroll
        for (int ks = 0; ks < 4; ++ks) {
          int g = ks * 4 + seg;
          bv0[ks] = *(short8v*)(h_bf + jj * 128 + ((g + jj) & 15) * 8);
          bv1[ks] = *(short8v*)(h_bf + (16 + jj) * 128 + ((g + 16 + jj) & 15) * 8);
        }
        float4v z = {0,0,0,0};
        a0A[q] = z; a0B[q] = z; a1A[q] = z; a1B[q] = z;
        a0A[q] = MFMA(afrA[0], bv0[0], a0A[q], 0, 0, 0);
        a0A[q] = MFMA(afrA[1], bv0[1], a0A[q], 0, 0, 0);
        a0B[q] = MFMA(afrA[2], bv0[2], a0B[q], 0, 0, 0);
        a0B[q] = MFMA(afrA[3], bv0[3], a0B[q], 0, 0, 0);
        a1A[q] = MFMA(afrA[0], bv1[0], a1A[q], 0, 0, 0);
        a1A[q] = MFMA(afrA[1], bv1[1], a1A[q], 0, 0, 0);
        a1B[q] = MFMA(afrA[2], bv1[2], a1B[q], 0, 0, 0);
        a1B[q] = MFMA(afrA[3], bv1[3], a1B[q], 0, 0, 0);
      }
      bar_lds();  // B1

      // ---- phase 2 (both batches): dl MFMAs, gam, update, publish ht
#pragma unroll
      for (int q = 0; q < 2; ++q) {
        const int b = b0 + q * 32;
        ushort* h_bf = pool + q * 4352;
        ushort* htb  = h_bf + 4096;
        ushort* LGb  = h_bf + 4224;

        short8v lb[4];
#pragma unroll
        for (int ks = 0; ks < 4; ++ks)
          lb[ks] = *(short8v*)(LGb + ks * 32 + seg * 8);
        float4v dl0 = bf4, dl1 = {0,0,0,0};
        dl0 = MFMA(alg[0], lb[0], dl0, 0, 0, 0);
        dl0 = MFMA(alg[1], lb[1], dl0, 0, 0, 0);
        dl1 = MFMA(alg[2], lb[2], dl1, 0, 0, 0);
        dl1 = MFMA(alg[3], lb[3], dl1, 0, 0, 0);

        float4v htp = {0,0,0,0};
#pragma unroll
        for (int nt = 0; nt < 2; ++nt) {
          float wvv = nt ? wv1[q] : wv0[q];
          float wnn = nt ? wn1[q] : wn0[q];
#pragma unroll
          for (int r = 0; r < 4; ++r) {
            float a = nt ? (a1A[q][r] + a1B[q][r]) : (a0A[q][r] + a0B[q][r]);
            float gam = sigm(a + dl0[r] + dl1[r]);
            float hn = fmaf(gam, hreg[q][nt][r], wvv * lgv[q][r]);
            hreg[q][nt][r] = hn;
            htp[r] = fmaf(wnn, hn, htp[r]);
          }
          int k = nt * 16 + jj;
          int p = ((n0 >> 3) + k) & 15;
          short4v pk;
#pragma unroll
          for (int r = 0; r < 4; ++r) pk[r] = (short)f2bfr(hreg[q][nt][r]);
          *(short4v*)(h_bf + k * 128 + p * 8 + (n0 & 7)) = pk;
        }
#pragma unroll
        for (int r = 0; r < 4; ++r) htp[r] = rsum16(htp[r]);
        if (jj == 0) {
          short4v hp;
#pragma unroll
          for (int r = 0; r < 4; ++r) hp[r] = (short)f2bfr(htp[r]);
          *(short4v*)(htb + n0) = hp;
          *(short4v*)(htsm + ((size_t)b * TT + t) * 128 + n0) = hp;
        }
        wv0[q] = wn0[q]; wv1[q] = wn1[q]; wn0[q] = wf0[q]; wn1[q] = wf1[q];
        xcg[q] = xng[q]; xcgg[q] = xngg[q]; xng[q] = xfg[q]; xngg[q] = xfgg[q];
      }
      bar_lds();  // B2
    }
  } else if (blockIdx.x < 64) {
    // ================= GRU (2 batches, ILP) =================
    __builtin_amdgcn_s_setprio(3);
    const int b0 = blockIdx.x - 32;

    short8v wfr[3][4];
    float4v bfr[3];
#pragma unroll
    for (int i = 0; i < 3; ++i) {
      int Mt = w + i * 8;
#pragma unroll
      for (int ks = 0; ks < 4; ++ks) {
        const float* src = Whh + (Mt * 16 + jj) * 128 + ks * 32 + seg * 8;
        short8v tv;
#pragma unroll
        for (int j = 0; j < 8; ++j) tv[j] = (short)f2bf(src[j]);
        wfr[i][ks] = tv;
      }
      bfr[i] = *(const float4v*)(bhh + Mt * 16 + seg * 4);
    }

    float4v hj4[2];
    const ushort* gpb[2];
    short4v xr_c[2], xz_c[2], xn_c[2], xr_n[2], xz_n[2], xn_n[2];
#pragma unroll
    for (int q = 0; q < 2; ++q) {
      hj4[q] = *(const float4v*)(h0v + n0);
      if (jj == 0) {
        short4v hp;
#pragma unroll
        for (int r = 0; r < 4; ++r) hp[r] = (short)f2bf(hj4[q][r]);
        *(short4v*)(pool + q * 256 + n0) = hp;
      }
    }
#pragma unroll
    for (int q = 0; q < 2; ++q) {
      const int b = b0 + q * 32;
      wait_flag(flags + b);
      gpb[q] = gxb + (size_t)b * TT * 384;
      xr_c[q] = *(const short4v*)(gpb[q] + n0);
      xz_c[q] = *(const short4v*)(gpb[q] + 128 + n0);
      xn_c[q] = *(const short4v*)(gpb[q] + 256 + n0);
      xr_n[q] = *(const short4v*)(gpb[q] + 384 + n0);
      xz_n[q] = *(const short4v*)(gpb[q] + 512 + n0);
      xn_n[q] = *(const short4v*)(gpb[q] + 640 + n0);
    }
    __syncthreads();

    for (int t = 0; t < TT - 1; ++t) {
      int tf = (t + 2 < TT - 1) ? (t + 2) : (TT - 2);
#pragma unroll
      for (int q = 0; q < 2; ++q) {
        const int b = b0 + q * 32;
        if ((tf & 31) == 0) wait_flag(flags + (tf >> 5) * 64 + b);
        const ushort* gf = gpb[q] + (size_t)tf * 384;
        short4v xr_f = *(const short4v*)(gf + n0);
        short4v xz_f = *(const short4v*)(gf + 128 + n0);
        short4v xn_f = *(const short4v*)(gf + 256 + n0);

        ushort* hb2 = pool + q * 256;
        const ushort* hsrc = hb2 + (t & 1) * 128;
        short8v bfrg[4];
#pragma unroll
        for (int ks = 0; ks < 4; ++ks)
          bfrg[ks] = *(short8v*)(hsrc + ks * 32 + seg * 8);

        float4v a0A = bfr[0], a1A = bfr[1], a2A = bfr[2];
        float4v a0B = {0,0,0,0}, a1B = {0,0,0,0}, a2B = {0,0,0,0};
        a0A = MFMA(wfr[0][0], bfrg[0], a0A, 0, 0, 0);
        a0A = MFMA(wfr[0][1], bfrg[1], a0A, 0, 0, 0);
        a0B = MFMA(wfr[0][2], bfrg[2], a0B, 0, 0, 0);
        a0B = MFMA(wfr[0][3], bfrg[3], a0B, 0, 0, 0);
        a1A = MFMA(wfr[1][0], bfrg[0], a1A, 0, 0, 0);
        a1A = MFMA(wfr[1][1], bfrg[1], a1A, 0, 0, 0);
        a1B = MFMA(wfr[1][2], bfrg[2], a1B, 0, 0, 0);
        a1B = MFMA(wfr[1][3], bfrg[3], a1B, 0, 0, 0);
        a2A = MFMA(wfr[2][0], bfrg[0], a2A, 0, 0, 0);
        a2A = MFMA(wfr[2][1], bfrg[1], a2A, 0, 0, 0);
        a2B = MFMA(wfr[2][2], bfrg[2], a2B, 0, 0, 0);
        a2B = MFMA(wfr[2][3], bfrg[3], a2B, 0, 0, 0);

        ushort* hdst = hb2 + ((t + 1) & 1) * 128;
        short4v hp;
#pragma unroll
        for (int r = 0; r < 4; ++r) {
          float rr = sigm(bf2f((ushort)xr_c[q][r]) + a0A[r] + a0B[r]);
          float zz = sigm(bf2f((ushort)xz_c[q][r]) + a1A[r] + a1B[r]);
          float nn = tanh_f(bf2f((ushort)xn_c[q][r]) + rr * (a2A[r] + a2B[r]));
          hj4[q][r] = fmaf(1.f - zz, nn, zz * hj4[q][r]);
          hp[r] = (short)f2bfr(hj4[q][r]);
        }
        if (jj == 0) {
          *(short4v*)(hdst + n0) = hp;
          *(short4v*)(htsg + ((size_t)b * TT + t) * 128 + n0) = hp;
        }
        xr_c[q] = xr_n[q]; xz_c[q] = xz_n[q]; xn_c[q] = xn_n[q];
        xr_n[q] = xr_f; xz_n[q] = xz_f; xn_n[q] = xn_f;
      }
      bar_lds();
    }
  } else {
    // ================= phase1 producer (chunk-major, unchanged) =========
    __builtin_amdgcn_s_setprio(0);
    const int gi = blockIdx.x - 64;
    const int chunk = gi >> 6, b = gi & 63;
    const int t0 = chunk * 32;
    const int NT = (TT - t0 < 32) ? (TT - t0) : 32;
    ushort* Xl = pool;
    ushort* Yl = pool + 13568;
    ushort* St = pool;
    const ushort* w1b  = wts;
    const ushort* w2b  = wts + 32768;
    const ushort* w3b  = wts + 81920;
    const ushort* wihb = wts + 114688;
    const ushort* keyb = wts + 163840;
    const ushort* wgb  = wts + 167936;

    {
      const int tok = tid >> 4, l16 = tid & 15;
      const int tsrc = (tok < NT) ? tok : (NT - 1);
      const int gt = b * TT + t0 + tsrc;
      const int e = e_data[gt], a = a_data[gt];
      const float* qrow = qm + (size_t)e * 101;
      float qv[7];
#pragma unroll
      for (int i = 0; i < 7; ++i) {
        int s = l16 + 16 * i;
        qv[i] = (s < 101) ? qrow[s] : 0.f;
      }
      const float* sbase = semb + l16 * 8;
      float4v acc0 = {0,0,0,0}, acc1 = {0,0,0,0};
      float cnt = 0.f;
#pragma unroll
      for (int i = 0; i < 7; ++i) {
        unsigned long long bal = __ballot(qv[i] != 0.f);
        unsigned m = (unsigned)((bal >> (tid & 48)) & 0xFFFFull);
        cnt += (float)__popc(m);
        while (m) {
          int s = 16 * i + __builtin_ctz(m);
          m &= m - 1;
          acc0 += *(const float4v*)(sbase + s * 128);
          acc1 += *(const float4v*)(sbase + s * 128 + 4);
        }
      }
      float inv = 1.f / fmaxf(cnt, 1.f);
      ushort* xr = Xl + tok * XS + l16 * 8;
#pragma unroll
      for (int r = 0; r < 4; ++r) { xr[r] = f2bf(acc0[r] * inv); xr[4 + r] = f2bf(acc1[r] * inv); }
      const float* ee = eemb + (size_t)e * 128 + l16 * 8;
      const float* ae = aemb + a * 128 + l16 * 8;
#pragma unroll
      for (int r = 0; r < 8; ++r) { xr[128 + r] = f2bf(ee[r]); xr[256 + r] = f2bf(ae[r]); }
    }
    __syncthreads();

    if (tid < 32) {
      int tau = tid;
      if (tau < NT) {
        const ushort* xr = Xl + tau * XS + 128;
        const float* wv = Wp + 256;
        float a0 = bp[0], a1 = 0.f, a2 = 0.f, a3 = 0.f;
        for (int j = 0; j < 128; j += 4) {
          a0 = fmaf(wv[j],     bf2f(xr[j]),     a0);
          a1 = fmaf(wv[j + 1], bf2f(xr[j + 1]), a1);
          a2 = fmaf(wv[j + 2], bf2f(xr[j + 2]), a2);
          a3 = fmaf(wv[j + 3], bf2f(xr[j + 3]), a3);
        }
        c1b[b * TT + t0 + tau] = (a0 + a1) + (a2 + a3);
      }
    }

    short8v axA[12], axB[12];
#pragma unroll
    for (int i = 0; i < 12; ++i) {
      axA[i] = *(short8v*)(Xl + jj * XS + i * 32 + seg * 8);
      axB[i] = *(short8v*)(Xl + (16 + jj) * XS + i * 32 + seg * 8);
    }

    for (int T = w; T < 24; T += 8) {
      float4v dA = {0,0,0,0}, dB = {0,0,0,0};
      float bv;
      if (T < 8) {
        const ushort* Bp = w1b + (T * 16 + jj) * 256 + seg * 8;
        bv = b1[T * 16 + jj];
#pragma unroll
        for (int k = 0; k < 8; ++k) {
          short8v bw = *(const short8v*)(Bp + k * 32);
          dA = MFMA(axA[k], bw, dA, 0, 0, 0);
          dB = MFMA(axB[k], bw, dB, 0, 0, 0);
        }
      } else if (T < 16) {
        const ushort* Bp = w2b + ((T - 8) * 16 + jj) * 384 + seg * 8;
        bv = b2[(T - 8) * 16 + jj];
#pragma unroll
        for (int k = 0; k < 12; ++k) {
          short8v bw = *(const short8v*)(Bp + k * 32);
          dA = MFMA(axA[k], bw, dA, 0, 0, 0);
          dB = MFMA(axB[k], bw, dB, 0, 0, 0);
        }
      } else {
        const ushort* Bp = w3b + ((T - 16) * 16 + jj) * 256 + seg * 8;
        bv = b3[(T - 16) * 16 + jj];
#pragma unroll
        for (int k = 0; k < 8; ++k) {
          short8v bw = *(const short8v*)(Bp + k * 32);
          dA = MFMA(axA[4 + k], bw, dA, 0, 0, 0);
          dB = MFMA(axB[4 + k], bw, dB, 0, 0, 0);
        }
      }
#pragma unroll
      for (int r = 0; r < 4; ++r) {
        float yA = dA[r] + bv, yB = dB[r] + bv;
        Yl[(seg * 4 + r) * XS + T * 16 + jj]      = f2bf(yA > 0.f ? yA : 0.f);
        Yl[(16 + seg * 4 + r) * XS + T * 16 + jj] = f2bf(yB > 0.f ? yB : 0.f);
      }
    }
    __syncthreads();

    short8v ayA[12], ayB[12];
#pragma unroll
    for (int i = 0; i < 12; ++i) {
      ayA[i] = *(short8v*)(Yl + jj * XS + i * 32 + seg * 8);
      ayB[i] = *(short8v*)(Yl + (16 + jj) * XS + i * 32 + seg * 8);
    }
    if (tid >= 32 && tid < 64) {
      int tau = tid - 32;
      if (tau < NT) {
        const ushort* xr = Yl + tau * XS;
        const float* wv = Wp1 + 256;
        float a0 = bp1[0], a1 = 0.f, a2 = 0.f, a3 = 0.f;
        for (int j = 0; j < 128; j += 4) {
          a0 = fmaf(wv[j],     bf2f(xr[j]),     a0);
          a1 = fmaf(wv[j + 1], bf2f(xr[j + 1]), a1);
          a2 = fmaf(wv[j + 2], bf2f(xr[j + 2]), a2);
          a3 = fmaf(wv[j + 3], bf2f(xr[j + 3]), a3);
        }
        c2b[b * TT + t0 + tau] = (a0 + a1) + (a2 + a3);
      }
    }
    __syncthreads();

    for (int T = w; T < 42; T += 8) {
      const ushort* Bp; int ai;
      if (T < 24)      { Bp = wihb + (T * 16 + jj) * 128 + seg * 8;        ai = 8; }
      else if (T < 40) { Bp = wgb  + ((T - 24) * 16 + jj) * 128 + seg * 8; ai = 4; }
      else             { Bp = keyb + ((T - 40) * 16 + jj) * 128 + seg * 8; ai = 0; }
      float4v dA = {0,0,0,0}, dB = {0,0,0,0};
#pragma unroll
      for (int k = 0; k < 4; ++k) {
        short8v bw = *(const short8v*)(Bp + k * 32);
        dA = MFMA(ayA[ai + k], bw, dA, 0, 0, 0);
        dB = MFMA(ayB[ai + k], bw, dB, 0, 0, 0);
      }
      if (T < 40) {
        float bv = (T < 24) ? bih[T * 16 + jj]
                 : (T < 32) ? bg[(T - 24) * 16 + jj] : bgg[(T - 32) * 16 + jj];
        int col = (T < 24) ? (T * 16 + jj) : (384 + (T - 24) * 16 + jj);
#pragma unroll
        for (int r = 0; r < 4; ++r) {
          St[(seg * 4 + r) * SS + col]      = f2bf(dA[r] + bv);
          St[(16 + seg * 4 + r) * SS + col] = f2bf(dB[r] + bv);
        }
      } else {
#pragma unroll
        for (int r = 0; r < 4; ++r) {
          int tokA = seg * 4 + r, tokB = 16 + seg * 4 + r;
          if (tokA < NT)
            wallb[((size_t)(b * TT + t0 + tokA)) * 32 + (T - 40) * 16 + jj] = dA[r];
          if (tokB < NT)
            wallb[((size_t)(b * TT + t0 + tokB)) * 32 + (T - 40) * 16 + jj] = dB[r];
        }
      }
    }
    __syncthreads();

    {
      const int tok = tid >> 4, sg = tid & 15;
      if (tok < NT) {
        size_t gt = (size_t)b * TT + t0 + tok;
#pragma unroll
        for (int p = 0; p < 3; ++p)
          *(short8v*)(gxb + gt * 384 + sg * 24 + p * 8) = *(short8v*)(St + tok * SS + sg * 24 + p * 8);
#pragma unroll
        for (int p = 0; p < 2; ++p)
          *(short8v*)(xgx + gt * 256 + sg * 16 + p * 8) = *(short8v*)(St + tok * SS + 384 + sg * 16 + p * 8);
      }
    }
    __syncthreads();
    if (tid == 0)
      __hip_atomic_store(flags + chunk * 64 + b, 1, __ATOMIC_RELEASE, __HIP_MEMORY_SCOPE_AGENT);
  }
}

// ---------------------------------------------------------------------------
// combine v2: 256 blocks (4/batch), 16 lanes per tau, vector loads + DPP reduce
// ---------------------------------------------------------------------------
__global__ __launch_bounds__(256) void combine_k(
    const ushort* __restrict__ htsg, const ushort* __restrict__ htsm,
    const float* __restrict__ c1b, const float* __restrict__ c2b,
    const float* __restrict__ Wp, const float* __restrict__ Wp1,
    float* __restrict__ out)
{
  const int b = blockIdx.x >> 2, q = blockIdx.x & 3;
  const int tid = threadIdx.x;
  const int wv = tid >> 6, l = tid & 63, slot = l >> 4, e = l & 15;
  float wpg[8], wpm[8], vpg[8], vpm[8];
#pragma unroll
  for (int r = 0; r < 8; ++r) {
    wpg[r] = Wp[e * 8 + r];  wpm[r] = Wp[128 + e * 8 + r];
    vpg[r] = Wp1[e * 8 + r]; vpm[r] = Wp1[128 + e * 8 + r];
  }
  if (q == 0 && tid == 0) out[(size_t)b * TT] = 0.f;
  const int tbeg = q * 125;
  const int tend = (tbeg + 125 < TT - 1) ? (tbeg + 125) : (TT - 1);
  for (int tau = tbeg + wv * 4 + slot; tau < tend; tau += 16) {
    size_t base = ((size_t)b * TT + tau) * 128;
    short8v hg = *(const short8v*)(htsg + base + e * 8);
    short8v hm = *(const short8v*)(htsm + base + e * 8);
    float qa = 0.f, qb = 0.f;
#pragma unroll
    for (int r = 0; r < 8; ++r) {
      float g = bf2f((ushort)hg[r]), m = bf2f((ushort)hm[r]);
      qa = fmaf(g, wpg[r], fmaf(m, wpm[r], qa));
      qb = fmaf(g, vpg[r], fmaf(m, vpm[r], qb));
    }
    qa = rsum16(qa);
    qb = rsum16(qb);
    if (e == 0) {
      size_t idx = (size_t)b * TT + tau + 1;
      out[idx] = sigm(qa + c1b[idx]) * sigm(qb + c2b[idx]);
    }
  }
}

// ---------------------------------------------------------------------------
extern "C" void kernel_launch(void* const* d_in, const int* in_sizes, int n_in,
                              void* d_out, int out_size, void* d_ws, size_t ws_size,
                              hipStream_t stream) {
  (void)in_sizes; (void)n_in; (void)out_size; (void)ws_size;
  const int* a_data = (const int*)d_in[1];
  const int* e_data = (const int*)d_in[2];
  const float* qm   = (const float*)d_in[4];
  const float* semb = (const float*)d_in[5];
  const float* aemb = (const float*)d_in[6];
  const float* eemb = (const float*)d_in[7];
  const float* W1 = (const float*)d_in[8];   const float* b1 = (const float*)d_in[9];
  const float* W2 = (const float*)d_in[10];  const float* b2 = (const float*)d_in[11];
  const float* W3 = (const float*)d_in[12];  const float* b3 = (const float*)d_in[13];
  const float* key = (const float*)d_in[14];
  const float* Wih = (const float*)d_in[15]; const float* Whh = (const float*)d_in[16];
  const float* bih = (const float*)d_in[17]; const float* bhh = (const float*)d_in[18];
  const float* Wg  = (const float*)d_in[19]; const float* bg  = (const float*)d_in[20];
  const float* Wgg = (const float*)d_in[21]; const float* bgg = (const float*)d_in[22];
  const float* Wf  = (const float*)d_in[23]; const float* bf_ = (const float*)d_in[24];
  const float* Wp  = (const float*)d_in[25]; const float* bp  = (const float*)d_in[26];
  const float* Wp1 = (const float*)d_in[27]; const float* bp1 = (const float*)d_in[28];
  const float* h0v = (const float*)d_in[29]; const float* m0  = (const float*)d_in[30];

  char* ws = (char*)d_ws;
  ushort* gxb  = (ushort*)(ws + 0);
  ushort* xgx  = (ushort*)(ws + 24576000);
  float* wallb = (float*)(ws + 40960000);
  ushort* htsm = (ushort*)(ws + 45056000);
  ushort* htsg = (ushort*)(ws + 53248000);
  float* c1b   = (float*)(ws + 61440000);
  float* c2b   = (float*)(ws + 61568000);
  ushort* wts  = (ushort*)(ws + 61696000);
  int* flags   = (int*)(ws + 62097408);
  float* out = (float*)d_out;

  hipMemsetAsync(flags, 0, 1024 * sizeof(int), stream);
  conv_k<<<dim3(784), dim3(256), 0, stream>>>(W1, W2, W3, Wih, key, Wg, Wgg, wts);
  mega_k<<<dim3(1088), dim3(512), 0, stream>>>(
      a_data, e_data, qm, semb, aemb, eemb, b1, b2, b3, bih, bg, bgg,
      Wp, bp, Wp1, bp1, wts, Wf, bf_, Wg, Wgg, Whh, bhh, h0v, m0,
      gxb, xgx, wallb, c1b, c2b, htsm, htsg, flags);
  combine_k<<<dim3(256), dim3(256), 0, stream>>>(
      htsg, htsm, c1b, c2b, Wp, Wp1, out);
}

// Round 6
// 793.962 us; speedup vs baseline: 3.1288x; 1.7229x over previous
//
#include <hip/hip_runtime.h>

#define TT 500
typedef __attribute__((ext_vector_type(8))) short short8v;
typedef __attribute__((ext_vector_type(4))) short short4v;
typedef __attribute__((ext_vector_type(4))) float float4v;
typedef unsigned short ushort;

__device__ __forceinline__ ushort f2bf(float f) {
  union { float f; unsigned u; } v; v.f = f;
  unsigned r = v.u + 0x7FFFu + ((v.u >> 16) & 1u);
  return (ushort)(r >> 16);
}
__device__ __forceinline__ ushort f2bfr(float f) {
  union { float f; unsigned u; } v; v.f = f;
  return (ushort)((v.u + 0x8000u) >> 16);
}
__device__ __forceinline__ float bf2f(ushort u) {
  union { unsigned u; float f; } v; v.u = ((unsigned)u) << 16;
  return v.f;
}
__device__ __forceinline__ float sigm(float x) {
  return __builtin_amdgcn_rcpf(1.f + __builtin_amdgcn_exp2f(-1.44269504088896341f * x));
}
__device__ __forceinline__ float tanh_f(float x) {
  return 1.f - 2.f * __builtin_amdgcn_rcpf(1.f + __builtin_amdgcn_exp2f(2.88539008177792682f * x));
}
__device__ __forceinline__ void bar_lds() {
  asm volatile("s_waitcnt lgkmcnt(0)\ns_barrier" ::: "memory");
}
template <int CTRL>
__device__ __forceinline__ float dppadd(float v) {
  int a = __builtin_amdgcn_update_dpp(0, __builtin_bit_cast(int, v), CTRL, 0xF, 0xF, true);
  return v + __builtin_bit_cast(float, a);
}
__device__ __forceinline__ float rsum16(float v) {
  v = dppadd<0xB1>(v);
  v = dppadd<0x4E>(v);
  v = dppadd<0x141>(v);
  v = dppadd<0x140>(v);
  return v;
}
__device__ __forceinline__ void wait_flag(int* f) {
  while (__hip_atomic_load(f, __ATOMIC_RELAXED, __HIP_MEMORY_SCOPE_AGENT) == 0)
    __builtin_amdgcn_s_sleep(8);
  __builtin_amdgcn_fence(__ATOMIC_ACQUIRE, "agent");
}
#define MFMA __builtin_amdgcn_mfma_f32_16x16x32_bf16

// ---------------------------------------------------------------------------
__global__ __launch_bounds__(256) void conv_k(
    const float* __restrict__ W1, const float* __restrict__ W2,
    const float* __restrict__ W3, const float* __restrict__ Wih,
    const float* __restrict__ key, const float* __restrict__ Wg,
    const float* __restrict__ Wgg, ushort* __restrict__ wts)
{
  int idx = blockIdx.x * 256 + threadIdx.x;
  if (idx >= 200704) return;
  float v;
  if (idx < 32768)       v = W1[idx];
  else if (idx < 81920)  v = W2[idx - 32768];
  else if (idx < 114688) v = W3[idx - 81920];
  else if (idx < 163840) v = Wih[idx - 114688];
  else if (idx < 167936) v = key[idx - 163840];
  else {
    int j = idx - 167936, o = j >> 7, k = j & 127;
    v = (o < 128) ? Wg[o * 256 + 128 + k] : Wgg[(o - 128) * 256 + 128 + k];
  }
  wts[idx] = f2bf(v);
}

// ---------------------------------------------------------------------------
// mega (r0-proven structure): blocks 0..63 mem-scan(b) | 64..127 GRU(b-64) |
// 128..1151 phase1 producers. Scan waves at s_setprio 3; producers at 0.
// r1-r4 experiments refuted the latency-hiding family (role-split / TLP /
// ILP all regressed): the scan step is ~70% wave-issue-bound (trans+gate
// VALU + 2 structural barriers). This build = r0 bit-identical math, with
// one scheduling nudge: bv0/bv1 LDS reads (dep only on h_bf, stable since
// B2) hoisted above dg/gg MFMAs so their latency hides under compute.
// ---------------------------------------------------------------------------
#define XS 424
#define SS 648

__global__ __launch_bounds__(512, 2) void mega_k(
    const int* __restrict__ a_data, const int* __restrict__ e_data,
    const float* __restrict__ qm, const float* __restrict__ semb,
    const float* __restrict__ aemb, const float* __restrict__ eemb,
    const float* __restrict__ b1, const float* __restrict__ b2,
    const float* __restrict__ b3, const float* __restrict__ bih,
    const float* __restrict__ bg, const float* __restrict__ bgg,
    const float* __restrict__ Wp, const float* __restrict__ bp,
    const float* __restrict__ Wp1, const float* __restrict__ bp1,
    const ushort* __restrict__ wts,
    const float* __restrict__ Wf, const float* __restrict__ bf_,
    const float* __restrict__ Wg, const float* __restrict__ Wgg,
    const float* __restrict__ Whh, const float* __restrict__ bhh,
    const float* __restrict__ h0v, const float* __restrict__ m0,
    ushort* __restrict__ gxb, ushort* __restrict__ xgx,
    float* __restrict__ wallb, float* __restrict__ c1b, float* __restrict__ c2b,
    ushort* __restrict__ htsm, ushort* __restrict__ htsg,
    int* __restrict__ flags)
{
  __shared__ __align__(16) ushort pool[27136];
  const int tid = threadIdx.x;
  const int w = tid >> 6, l = tid & 63, jj = l & 15, seg = l >> 4;
  const int n0 = w * 16 + seg * 4;

  if (blockIdx.x < 64) {
    // ================= memory scan =================
    __builtin_amdgcn_s_setprio(3);
    const int b = blockIdx.x;
    ushort* h_bf = pool;
    ushort* htb  = pool + 4096;
    ushort* LGb  = pool + 4224;

    short8v afrA[4], aggA[4], aggB[4], alg[4];
#pragma unroll
    for (int ks = 0; ks < 4; ++ks) {
      const float* sA = Wf  + (w * 16 + jj) * 256 + ks * 32 + seg * 8;
      const float* sB = Wg  + (w * 16 + jj) * 256 + ks * 32 + seg * 8;
      const float* sC = Wgg + (w * 16 + jj) * 256 + ks * 32 + seg * 8;
      const float* sD = Wf  + (w * 16 + jj) * 256 + 128 + ks * 32 + seg * 8;
      short8v a, bb, c, d;
#pragma unroll
      for (int j = 0; j < 8; ++j) {
        a[j] = (short)f2bf(sA[j]); bb[j] = (short)f2bf(sB[j]);
        c[j] = (short)f2bf(sC[j]); d[j] = (short)f2bf(sD[j]);
      }
      afrA[ks] = a; aggA[ks] = bb; aggB[ks] = c; alg[ks] = d;
    }
    const float4v bf4 = *(const float4v*)(bf_ + n0);

    float hreg[2][4];
#pragma unroll
    for (int nt = 0; nt < 2; ++nt) {
      int k = nt * 16 + jj;
      float4v m = *(const float4v*)(m0 + k * 128 + n0);
#pragma unroll
      for (int r = 0; r < 4; ++r) hreg[nt][r] = m[r];
      int p = ((n0 >> 3) + k) & 15;
      short4v pk;
#pragma unroll
      for (int r = 0; r < 4; ++r) pk[r] = (short)f2bf(hreg[nt][r]);
      *(short4v*)(h_bf + k * 128 + p * 8 + (n0 & 7)) = pk;
    }
    wait_flag(flags + b);
    const float* wl = wallb + (size_t)b * TT * 32;
    const ushort* xgp = xgx + (size_t)b * TT * 256;
    float wv0 = wl[jj], wv1 = wl[16 + jj];
    float wn0 = wl[32 + jj], wn1 = wl[48 + jj];
    short4v xcg  = *(const short4v*)(xgp + n0);
    short4v xcgg = *(const short4v*)(xgp + 128 + n0);
    short4v xng  = *(const short4v*)(xgp + 256 + n0);
    short4v xngg = *(const short4v*)(xgp + 384 + n0);
    {
      float4v htp;
#pragma unroll
      for (int r = 0; r < 4; ++r)
        htp[r] = rsum16(wv0 * hreg[0][r] + wv1 * hreg[1][r]);
      if (jj == 0) {
        short4v hp;
#pragma unroll
        for (int r = 0; r < 4; ++r) hp[r] = (short)f2bf(htp[r]);
        *(short4v*)(htb + n0) = hp;
      }
    }
    __syncthreads();

    for (int t = 0; t < TT - 1; ++t) {
      int tw = (t + 2 <= TT - 1) ? (t + 2) : (TT - 1);
      if ((tw & 31) == 0) wait_flag(flags + (tw >> 5) * 64 + b);
      float wf0 = wl[tw * 32 + jj], wf1 = wl[tw * 32 + 16 + jj];
      short4v xfg  = *(const short4v*)(xgp + (size_t)tw * 256 + n0);
      short4v xfgg = *(const short4v*)(xgp + (size_t)tw * 256 + 128 + n0);

      short8v hb[4];
#pragma unroll
      for (int ks = 0; ks < 4; ++ks)
        hb[ks] = *(short8v*)(htb + ks * 32 + seg * 8);

      // bv reads hoisted: depend only on h_bf (stable since B2); latency
      // hides under the dg/gg MFMAs and lgv transcendentals below.
      short8v bv0[4], bv1[4];
#pragma unroll
      for (int ks = 0; ks < 4; ++ks) {
        int g = ks * 4 + seg;
        bv0[ks] = *(short8v*)(h_bf + jj * 128 + ((g + jj) & 15) * 8);
        bv1[ks] = *(short8v*)(h_bf + (16 + jj) * 128 + ((g + 16 + jj) & 15) * 8);
      }

      float4v xg4, xgg4;
#pragma unroll
      for (int r = 0; r < 4; ++r) { xg4[r] = bf2f((ushort)xcg[r]); xgg4[r] = bf2f((ushort)xcgg[r]); }
      float4v dg0 = xg4, dg1 = {0,0,0,0}, gg0 = xgg4, gg1 = {0,0,0,0};
      dg0 = MFMA(aggA[0], hb[0], dg0, 0, 0, 0);
      dg0 = MFMA(aggA[1], hb[1], dg0, 0, 0, 0);
      dg1 = MFMA(aggA[2], hb[2], dg1, 0, 0, 0);
      dg1 = MFMA(aggA[3], hb[3], dg1, 0, 0, 0);
      gg0 = MFMA(aggB[0], hb[0], gg0, 0, 0, 0);
      gg0 = MFMA(aggB[1], hb[1], gg0, 0, 0, 0);
      gg1 = MFMA(aggB[2], hb[2], gg1, 0, 0, 0);
      gg1 = MFMA(aggB[3], hb[3], gg1, 0, 0, 0);

      float lgv[4];
#pragma unroll
      for (int r = 0; r < 4; ++r)
        lgv[r] = tanh_f(dg0[r] + dg1[r]) * sigm(gg0[r] + gg1[r]);
      if (jj == 0) {
        short4v lp;
#pragma unroll
        for (int r = 0; r < 4; ++r) lp[r] = (short)f2bfr(lgv[r]);
        *(short4v*)(LGb + n0) = lp;
      }

      float4v a0A = {0,0,0,0}, a0B = {0,0,0,0}, a1A = {0,0,0,0}, a1B = {0,0,0,0};
      a0A = MFMA(afrA[0], bv0[0], a0A, 0, 0, 0);
      a0A = MFMA(afrA[1], bv0[1], a0A, 0, 0, 0);
      a0B = MFMA(afrA[2], bv0[2], a0B, 0, 0, 0);
      a0B = MFMA(afrA[3], bv0[3], a0B, 0, 0, 0);
      a1A = MFMA(afrA[0], bv1[0], a1A, 0, 0, 0);
      a1A = MFMA(afrA[1], bv1[1], a1A, 0, 0, 0);
      a1B = MFMA(afrA[2], bv1[2], a1B, 0, 0, 0);
      a1B = MFMA(afrA[3], bv1[3], a1B, 0, 0, 0);
      bar_lds();  // B1

      short8v lb[4];
#pragma unroll
      for (int ks = 0; ks < 4; ++ks)
        lb[ks] = *(short8v*)(LGb + ks * 32 + seg * 8);
      float4v dl0 = bf4, dl1 = {0,0,0,0};
      dl0 = MFMA(alg[0], lb[0], dl0, 0, 0, 0);
      dl0 = MFMA(alg[1], lb[1], dl0, 0, 0, 0);
      dl1 = MFMA(alg[2], lb[2], dl1, 0, 0, 0);
      dl1 = MFMA(alg[3], lb[3], dl1, 0, 0, 0);

      float4v htp = {0,0,0,0};
#pragma unroll
      for (int nt = 0; nt < 2; ++nt) {
        float wvv = nt ? wv1 : wv0;
        float wnn = nt ? wn1 : wn0;
#pragma unroll
        for (int r = 0; r < 4; ++r) {
          float a = nt ? (a1A[r] + a1B[r]) : (a0A[r] + a0B[r]);
          float gam = sigm(a + dl0[r] + dl1[r]);
          float hn = fmaf(gam, hreg[nt][r], wvv * lgv[r]);
          hreg[nt][r] = hn;
          htp[r] = fmaf(wnn, hn, htp[r]);
        }
        int k = nt * 16 + jj;
        int p = ((n0 >> 3) + k) & 15;
        short4v pk;
#pragma unroll
        for (int r = 0; r < 4; ++r) pk[r] = (short)f2bfr(hreg[nt][r]);
        *(short4v*)(h_bf + k * 128 + p * 8 + (n0 & 7)) = pk;
      }
#pragma unroll
      for (int r = 0; r < 4; ++r) htp[r] = rsum16(htp[r]);
      if (jj == 0) {
        short4v hp;
#pragma unroll
        for (int r = 0; r < 4; ++r) hp[r] = (short)f2bfr(htp[r]);
        *(short4v*)(htb + n0) = hp;
        *(short4v*)(htsm + ((size_t)b * TT + t) * 128 + n0) = hp;
      }
      wv0 = wn0; wv1 = wn1; wn0 = wf0; wn1 = wf1;
      xcg = xng; xcgg = xngg; xng = xfg; xngg = xfgg;
      bar_lds();  // B2
    }
  } else if (blockIdx.x < 128) {
    // ================= GRU =================
    __builtin_amdgcn_s_setprio(3);
    const int b = blockIdx.x - 64;
    ushort* hb2 = pool;

    short8v wfr[3][4];
    float4v bfr[3];
#pragma unroll
    for (int i = 0; i < 3; ++i) {
      int Mt = w + i * 8;
#pragma unroll
      for (int ks = 0; ks < 4; ++ks) {
        const float* src = Whh + (Mt * 16 + jj) * 128 + ks * 32 + seg * 8;
        short8v tv;
#pragma unroll
        for (int j = 0; j < 8; ++j) tv[j] = (short)f2bf(src[j]);
        wfr[i][ks] = tv;
      }
      bfr[i] = *(const float4v*)(bhh + Mt * 16 + seg * 4);
    }
    float4v hj4 = *(const float4v*)(h0v + n0);
    if (jj == 0) {
      short4v hp;
#pragma unroll
      for (int r = 0; r < 4; ++r) hp[r] = (short)f2bf(hj4[r]);
      *(short4v*)(hb2 + n0) = hp;
    }
    wait_flag(flags + b);
    const ushort* gpb = gxb + (size_t)b * TT * 384;
    short4v xr_c = *(const short4v*)(gpb + n0);
    short4v xz_c = *(const short4v*)(gpb + 128 + n0);
    short4v xn_c = *(const short4v*)(gpb + 256 + n0);
    short4v xr_n = *(const short4v*)(gpb + 384 + n0);
    short4v xz_n = *(const short4v*)(gpb + 512 + n0);
    short4v xn_n = *(const short4v*)(gpb + 640 + n0);
    __syncthreads();

    for (int t = 0; t < TT - 1; ++t) {
      int tf = (t + 2 < TT - 1) ? (t + 2) : (TT - 2);
      if ((tf & 31) == 0) wait_flag(flags + (tf >> 5) * 64 + b);
      const ushort* gf = gpb + (size_t)tf * 384;
      short4v xr_f = *(const short4v*)(gf + n0);
      short4v xz_f = *(const short4v*)(gf + 128 + n0);
      short4v xn_f = *(const short4v*)(gf + 256 + n0);

      const ushort* hsrc = hb2 + (t & 1) * 128;
      short8v bfrg[4];
#pragma unroll
      for (int ks = 0; ks < 4; ++ks)
        bfrg[ks] = *(short8v*)(hsrc + ks * 32 + seg * 8);

      float4v a0A = bfr[0], a1A = bfr[1], a2A = bfr[2];
      float4v a0B = {0,0,0,0}, a1B = {0,0,0,0}, a2B = {0,0,0,0};
      a0A = MFMA(wfr[0][0], bfrg[0], a0A, 0, 0, 0);
      a0A = MFMA(wfr[0][1], bfrg[1], a0A, 0, 0, 0);
      a0B = MFMA(wfr[0][2], bfrg[2], a0B, 0, 0, 0);
      a0B = MFMA(wfr[0][3], bfrg[3], a0B, 0, 0, 0);
      a1A = MFMA(wfr[1][0], bfrg[0], a1A, 0, 0, 0);
      a1A = MFMA(wfr[1][1], bfrg[1], a1A, 0, 0, 0);
      a1B = MFMA(wfr[1][2], bfrg[2], a1B, 0, 0, 0);
      a1B = MFMA(wfr[1][3], bfrg[3], a1B, 0, 0, 0);
      a2A = MFMA(wfr[2][0], bfrg[0], a2A, 0, 0, 0);
      a2A = MFMA(wfr[2][1], bfrg[1], a2A, 0, 0, 0);
      a2B = MFMA(wfr[2][2], bfrg[2], a2B, 0, 0, 0);
      a2B = MFMA(wfr[2][3], bfrg[3], a2B, 0, 0, 0);

      ushort* hdst = hb2 + ((t + 1) & 1) * 128;
      short4v hp;
#pragma unroll
      for (int r = 0; r < 4; ++r) {
        float rr = sigm(bf2f((ushort)xr_c[r]) + a0A[r] + a0B[r]);
        float zz = sigm(bf2f((ushort)xz_c[r]) + a1A[r] + a1B[r]);
        float nn = tanh_f(bf2f((ushort)xn_c[r]) + rr * (a2A[r] + a2B[r]));
        hj4[r] = fmaf(1.f - zz, nn, zz * hj4[r]);
        hp[r] = (short)f2bfr(hj4[r]);
      }
      if (jj == 0) {
        *(short4v*)(hdst + n0) = hp;
        *(short4v*)(htsg + ((size_t)b * TT + t) * 128 + n0) = hp;
      }
      xr_c = xr_n; xz_c = xz_n; xn_c = xn_n;
      xr_n = xr_f; xz_n = xz_f; xn_n = xn_f;
      bar_lds();
    }
  } else {
    // ================= phase1 producer (chunk-major) =================
    __builtin_amdgcn_s_setprio(0);
    const int gi = blockIdx.x - 128;
    const int chunk = gi >> 6, b = gi & 63;
    const int t0 = chunk * 32;
    const int NT = (TT - t0 < 32) ? (TT - t0) : 32;
    ushort* Xl = pool;
    ushort* Yl = pool + 13568;
    ushort* St = pool;
    const ushort* w1b  = wts;
    const ushort* w2b  = wts + 32768;
    const ushort* w3b  = wts + 81920;
    const ushort* wihb = wts + 114688;
    const ushort* keyb = wts + 163840;
    const ushort* wgb  = wts + 167936;

    {
      const int tok = tid >> 4, l16 = tid & 15;
      const int tsrc = (tok < NT) ? tok : (NT - 1);
      const int gt = b * TT + t0 + tsrc;
      const int e = e_data[gt], a = a_data[gt];
      const float* qrow = qm + (size_t)e * 101;
      float qv[7];
#pragma unroll
      for (int i = 0; i < 7; ++i) {
        int s = l16 + 16 * i;
        qv[i] = (s < 101) ? qrow[s] : 0.f;
      }
      const float* sbase = semb + l16 * 8;
      float4v acc0 = {0,0,0,0}, acc1 = {0,0,0,0};
      float cnt = 0.f;
#pragma unroll
      for (int i = 0; i < 7; ++i) {
        unsigned long long bal = __ballot(qv[i] != 0.f);
        unsigned m = (unsigned)((bal >> (tid & 48)) & 0xFFFFull);
        cnt += (float)__popc(m);
        while (m) {
          int s = 16 * i + __builtin_ctz(m);
          m &= m - 1;
          acc0 += *(const float4v*)(sbase + s * 128);
          acc1 += *(const float4v*)(sbase + s * 128 + 4);
        }
      }
      float inv = 1.f / fmaxf(cnt, 1.f);
      ushort* xr = Xl + tok * XS + l16 * 8;
#pragma unroll
      for (int r = 0; r < 4; ++r) { xr[r] = f2bf(acc0[r] * inv); xr[4 + r] = f2bf(acc1[r] * inv); }
      const float* ee = eemb + (size_t)e * 128 + l16 * 8;
      const float* ae = aemb + a * 128 + l16 * 8;
#pragma unroll
      for (int r = 0; r < 8; ++r) { xr[128 + r] = f2bf(ee[r]); xr[256 + r] = f2bf(ae[r]); }
    }
    __syncthreads();

    if (tid < 32) {
      int tau = tid;
      if (tau < NT) {
        const ushort* xr = Xl + tau * XS + 128;
        const float* wv = Wp + 256;
        float a0 = bp[0], a1 = 0.f, a2 = 0.f, a3 = 0.f;
        for (int j = 0; j < 128; j += 4) {
          a0 = fmaf(wv[j],     bf2f(xr[j]),     a0);
          a1 = fmaf(wv[j + 1], bf2f(xr[j + 1]), a1);
          a2 = fmaf(wv[j + 2], bf2f(xr[j + 2]), a2);
          a3 = fmaf(wv[j + 3], bf2f(xr[j + 3]), a3);
        }
        c1b[b * TT + t0 + tau] = (a0 + a1) + (a2 + a3);
      }
    }

    short8v axA[12], axB[12];
#pragma unroll
    for (int i = 0; i < 12; ++i) {
      axA[i] = *(short8v*)(Xl + jj * XS + i * 32 + seg * 8);
      axB[i] = *(short8v*)(Xl + (16 + jj) * XS + i * 32 + seg * 8);
    }

    for (int T = w; T < 24; T += 8) {
      float4v dA = {0,0,0,0}, dB = {0,0,0,0};
      float bv;
      if (T < 8) {
        const ushort* Bp = w1b + (T * 16 + jj) * 256 + seg * 8;
        bv = b1[T * 16 + jj];
#pragma unroll
        for (int k = 0; k < 8; ++k) {
          short8v bw = *(const short8v*)(Bp + k * 32);
          dA = MFMA(axA[k], bw, dA, 0, 0, 0);
          dB = MFMA(axB[k], bw, dB, 0, 0, 0);
        }
      } else if (T < 16) {
        const ushort* Bp = w2b + ((T - 8) * 16 + jj) * 384 + seg * 8;
        bv = b2[(T - 8) * 16 + jj];
#pragma unroll
        for (int k = 0; k < 12; ++k) {
          short8v bw = *(const short8v*)(Bp + k * 32);
          dA = MFMA(axA[k], bw, dA, 0, 0, 0);
          dB = MFMA(axB[k], bw, dB, 0, 0, 0);
        }
      } else {
        const ushort* Bp = w3b + ((T - 16) * 16 + jj) * 256 + seg * 8;
        bv = b3[(T - 16) * 16 + jj];
#pragma unroll
        for (int k = 0; k < 8; ++k) {
          short8v bw = *(const short8v*)(Bp + k * 32);
          dA = MFMA(axA[4 + k], bw, dA, 0, 0, 0);
          dB = MFMA(axB[4 + k], bw, dB, 0, 0, 0);
        }
      }
#pragma unroll
      for (int r = 0; r < 4; ++r) {
        float yA = dA[r] + bv, yB = dB[r] + bv;
        Yl[(seg * 4 + r) * XS + T * 16 + jj]      = f2bf(yA > 0.f ? yA : 0.f);
        Yl[(16 + seg * 4 + r) * XS + T * 16 + jj] = f2bf(yB > 0.f ? yB : 0.f);
      }
    }
    __syncthreads();

    short8v ayA[12], ayB[12];
#pragma unroll
    for (int i = 0; i < 12; ++i) {
      ayA[i] = *(short8v*)(Yl + jj * XS + i * 32 + seg * 8);
      ayB[i] = *(short8v*)(Yl + (16 + jj) * XS + i * 32 + seg * 8);
    }
    if (tid >= 32 && tid < 64) {
      int tau = tid - 32;
      if (tau < NT) {
        const ushort* xr = Yl + tau * XS;
        const float* wv = Wp1 + 256;
        float a0 = bp1[0], a1 = 0.f, a2 = 0.f, a3 = 0.f;
        for (int j = 0; j < 128; j += 4) {
          a0 = fmaf(wv[j],     bf2f(xr[j]),     a0);
          a1 = fmaf(wv[j + 1], bf2f(xr[j + 1]), a1);
          a2 = fmaf(wv[j + 2], bf2f(xr[j + 2]), a2);
          a3 = fmaf(wv[j + 3], bf2f(xr[j + 3]), a3);
        }
        c2b[b * TT + t0 + tau] = (a0 + a1) + (a2 + a3);
      }
    }
    __syncthreads();

    for (int T = w; T < 42; T += 8) {
      const ushort* Bp; int ai;
      if (T < 24)      { Bp = wihb + (T * 16 + jj) * 128 + seg * 8;        ai = 8; }
      else if (T < 40) { Bp = wgb  + ((T - 24) * 16 + jj) * 128 + seg * 8; ai = 4; }
      else             { Bp = keyb + ((T - 40) * 16 + jj) * 128 + seg * 8; ai = 0; }
      float4v dA = {0,0,0,0}, dB = {0,0,0,0};
#pragma unroll
      for (int k = 0; k < 4; ++k) {
        short8v bw = *(const short8v*)(Bp + k * 32);
        dA = MFMA(ayA[ai + k], bw, dA, 0, 0, 0);
        dB = MFMA(ayB[ai + k], bw, dB, 0, 0, 0);
      }
      if (T < 40) {
        float bv = (T < 24) ? bih[T * 16 + jj]
                 : (T < 32) ? bg[(T - 24) * 16 + jj] : bgg[(T - 32) * 16 + jj];
        int col = (T < 24) ? (T * 16 + jj) : (384 + (T - 24) * 16 + jj);
#pragma unroll
        for (int r = 0; r < 4; ++r) {
          St[(seg * 4 + r) * SS + col]      = f2bf(dA[r] + bv);
          St[(16 + seg * 4 + r) * SS + col] = f2bf(dB[r] + bv);
        }
      } else {
#pragma unroll
        for (int r = 0; r < 4; ++r) {
          int tokA = seg * 4 + r, tokB = 16 + seg * 4 + r;
          if (tokA < NT)
            wallb[((size_t)(b * TT + t0 + tokA)) * 32 + (T - 40) * 16 + jj] = dA[r];
          if (tokB < NT)
            wallb[((size_t)(b * TT + t0 + tokB)) * 32 + (T - 40) * 16 + jj] = dB[r];
        }
      }
    }
    __syncthreads();

    {
      const int tok = tid >> 4, sg = tid & 15;
      if (tok < NT) {
        size_t gt = (size_t)b * TT + t0 + tok;
#pragma unroll
        for (int p = 0; p < 3; ++p)
          *(short8v*)(gxb + gt * 384 + sg * 24 + p * 8) = *(short8v*)(St + tok * SS + sg * 24 + p * 8);
#pragma unroll
        for (int p = 0; p < 2; ++p)
          *(short8v*)(xgx + gt * 256 + sg * 16 + p * 8) = *(short8v*)(St + tok * SS + 384 + sg * 16 + p * 8);
      }
    }
    __syncthreads();
    if (tid == 0)
      __hip_atomic_store(flags + chunk * 64 + b, 1, __ATOMIC_RELEASE, __HIP_MEMORY_SCOPE_AGENT);
  }
}

// ---------------------------------------------------------------------------
// combine v2: 256 blocks (4/batch), 16 lanes per tau, vector loads + DPP reduce
// ---------------------------------------------------------------------------
__global__ __launch_bounds__(256) void combine_k(
    const ushort* __restrict__ htsg, const ushort* __restrict__ htsm,
    const float* __restrict__ c1b, const float* __restrict__ c2b,
    const float* __restrict__ Wp, const float* __restrict__ Wp1,
    float* __restrict__ out)
{
  const int b = blockIdx.x >> 2, q = blockIdx.x & 3;
  const int tid = threadIdx.x;
  const int wv = tid >> 6, l = tid & 63, slot = l >> 4, e = l & 15;
  float wpg[8], wpm[8], vpg[8], vpm[8];
#pragma unroll
  for (int r = 0; r < 8; ++r) {
    wpg[r] = Wp[e * 8 + r];  wpm[r] = Wp[128 + e * 8 + r];
    vpg[r] = Wp1[e * 8 + r]; vpm[r] = Wp1[128 + e * 8 + r];
  }
  if (q == 0 && tid == 0) out[(size_t)b * TT] = 0.f;
  const int tbeg = q * 125;
  const int tend = (tbeg + 125 < TT - 1) ? (tbeg + 125) : (TT - 1);
  for (int tau = tbeg + wv * 4 + slot; tau < tend; tau += 16) {
    size_t base = ((size_t)b * TT + tau) * 128;
    short8v hg = *(const short8v*)(htsg + base + e * 8);
    short8v hm = *(const short8v*)(htsm + base + e * 8);
    float qa = 0.f, qb = 0.f;
#pragma unroll
    for (int r = 0; r < 8; ++r) {
      float g = bf2f((ushort)hg[r]), m = bf2f((ushort)hm[r]);
      qa = fmaf(g, wpg[r], fmaf(m, wpm[r], qa));
      qb = fmaf(g, vpg[r], fmaf(m, vpm[r], qb));
    }
    qa = rsum16(qa);
    qb = rsum16(qb);
    if (e == 0) {
      size_t idx = (size_t)b * TT + tau + 1;
      out[idx] = sigm(qa + c1b[idx]) * sigm(qb + c2b[idx]);
    }
  }
}

// ---------------------------------------------------------------------------
extern "C" void kernel_launch(void* const* d_in, const int* in_sizes, int n_in,
                              void* d_out, int out_size, void* d_ws, size_t ws_size,
                              hipStream_t stream) {
  (void)in_sizes; (void)n_in; (void)out_size; (void)ws_size;
  const int* a_data = (const int*)d_in[1];
  const int* e_data = (const int*)d_in[2];
  const float* qm   = (const float*)d_in[4];
  const float* semb = (const float*)d_in[5];
  const float* aemb = (const float*)d_in[6];
  const float* eemb = (const float*)d_in[7];
  const float* W1 = (const float*)d_in[8];   const float* b1 = (const float*)d_in[9];
  const float* W2 = (const float*)d_in[10];  const float* b2 = (const float*)d_in[11];
  const float* W3 = (const float*)d_in[12];  const float* b3 = (const float*)d_in[13];
  const float* key = (const float*)d_in[14];
  const float* Wih = (const float*)d_in[15]; const float* Whh = (const float*)d_in[16];
  const float* bih = (const float*)d_in[17]; const float* bhh = (const float*)d_in[18];
  const float* Wg  = (const float*)d_in[19]; const float* bg  = (const float*)d_in[20];
  const float* Wgg = (const float*)d_in[21]; const float* bgg = (const float*)d_in[22];
  const float* Wf  = (const float*)d_in[23]; const float* bf_ = (const float*)d_in[24];
  const float* Wp  = (const float*)d_in[25]; const float* bp  = (const float*)d_in[26];
  const float* Wp1 = (const float*)d_in[27]; const float* bp1 = (const float*)d_in[28];
  const float* h0v = (const float*)d_in[29]; const float* m0  = (const float*)d_in[30];

  char* ws = (char*)d_ws;
  ushort* gxb  = (ushort*)(ws + 0);
  ushort* xgx  = (ushort*)(ws + 24576000);
  float* wallb = (float*)(ws + 40960000);
  ushort* htsm = (ushort*)(ws + 45056000);
  ushort* htsg = (ushort*)(ws + 53248000);
  float* c1b   = (float*)(ws + 61440000);
  float* c2b   = (float*)(ws + 61568000);
  ushort* wts  = (ushort*)(ws + 61696000);
  int* flags   = (int*)(ws + 62097408);
  float* out = (float*)d_out;

  hipMemsetAsync(flags, 0, 1024 * sizeof(int), stream);
  conv_k<<<dim3(784), dim3(256), 0, stream>>>(W1, W2, W3, Wih, key, Wg, Wgg, wts);
  mega_k<<<dim3(1152), dim3(512), 0, stream>>>(
      a_data, e_data, qm, semb, aemb, eemb, b1, b2, b3, bih, bg, bgg,
      Wp, bp, Wp1, bp1, wts, Wf, bf_, Wg, Wgg, Whh, bhh, h0v, m0,
      gxb, xgx, wallb, c1b, c2b, htsm, htsg, flags);
  combine_k<<<dim3(256), dim3(256), 0, stream>>>(
      htsg, htsm, c1b, c2b, Wp, Wp1, out);
}